// Round 8
// baseline (901.730 us; speedup 1.0000x reference)
//
#include <hip/hip_runtime.h>

// Problem constants
#define NB    64      // batch
#define LCAP  51      // caption length
#define TT    50      // decode steps
#define HID   512
#define EMB   512
#define VOC   30000
#define ENCD  2048
#define G4    2048    // 4*HID

typedef unsigned short u16;
typedef unsigned int   u32;
typedef __attribute__((ext_vector_type(8))) short bf16x8;
typedef __attribute__((ext_vector_type(4))) float f32x4;
typedef __attribute__((ext_vector_type(4))) unsigned int u32x4;

__device__ __forceinline__ u16 f2bf(float x) {
  union { float f; unsigned u; } v; v.f = x;
  unsigned r = v.u + 0x7fffu + ((v.u >> 16) & 1u);
  return (u16)(r >> 16);
}

__device__ __forceinline__ float fast_sigmoid(float x) {
  return 1.f / (1.f + __expf(-x));
}
__device__ __forceinline__ float fast_tanh(float x) {
  float xx = fminf(fmaxf(x, -10.f), 10.f);
  float e = __expf(2.f * xx);
  return (e - 1.f) * __frcp_rn(e + 1.f);
}

// 16-lane poll over the single 64B byte-flag line: wait until all 64 byte
// flags >= tt. One line-request per block per iteration.
// SLEEP: latency-critical LSTM pollers use 1 (~64cy); FC pollers use 64
// (~1.7us) -- r1/r4 proved fast polling from many blocks congests the MALL.
template <int SLEEP>
__device__ __forceinline__ void poll_flags16(const int* flg, int lane, u32 tt) {
  if (lane < 16) {
    const u32* myp = (const u32*)flg + lane;
    u32 f;
    for (;;) {
      asm volatile("global_load_dword %0, %1, off sc0 sc1"
                   : "=v"(f) : "v"(myp) : "memory");
      asm volatile("s_waitcnt vmcnt(0)" : "+v"(f) :: "memory");
      if (((f & 0xffu) >= tt) & (((f >> 8) & 0xffu) >= tt) &
          (((f >> 16) & 0xffu) >= tt) & ((f >> 24) >= tt)) break;
      __builtin_amdgcn_s_sleep(SLEEP);
    }
  }
}

// ---------------- sort + int outputs + t-major compaction + flag init ----------------
// Batches sorted by length DESC => active set at time t is a prefix b<cnt[t].
// t-major active list trow[k] (t ascending, b ascending within t) gives FC
// tiles a MONOTONE flag threshold tileneed[i] = t_of_last_row(i) + 2.
__global__ __launch_bounds__(256) void sort_k(const int* __restrict__ cap_len,
                                              const int* __restrict__ caps,
                                              float* __restrict__ out,
                                              int* __restrict__ sind,
                                              int* __restrict__ dlen,
                                              int* __restrict__ trow,
                                              int* __restrict__ zmap,
                                              int* __restrict__ nact,
                                              int* __restrict__ flags,
                                              int* __restrict__ tileneed) {
  __shared__ int smlen[NB];
  __shared__ int smpos[NB];
  __shared__ int sdl[NB];
  __shared__ int cnt_s[TT];
  __shared__ int toff_s[TT];
  __shared__ int trow_s[NB * TT];
  int tid = threadIdx.x;
  if (tid < NB) { smlen[tid] = cap_len[tid]; flags[tid] = 0; }
  __syncthreads();
  if (tid < NB) {
    int li = smlen[tid];
    int rank = 0;
    for (int j = 0; j < NB; ++j) {
      int lj = smlen[j];
      rank += (lj > li || (lj == li && j < tid)) ? 1 : 0;
    }
    smpos[rank] = tid;
  }
  __syncthreads();
  if (tid < NB) {
    int src = smpos[tid];
    int dl = smlen[src] - 1;
    sind[tid] = src;
    dlen[tid] = dl;
    sdl[tid] = dl;
    float* caps_out = out + (size_t)NB * TT * VOC;          // 96,000,000
    for (int l = 0; l < LCAP; ++l)
      caps_out[tid * LCAP + l] = (float)caps[src * LCAP + l];
    out[96003264 + tid] = (float)dl;       // dec_len
    out[96003328 + tid] = (float)src;      // sort_ind
  }
  __syncthreads();
  if (tid < TT) {
    int c = 0;
    for (int b = 0; b < NB; ++b) c += (sdl[b] > tid) ? 1 : 0;
    cnt_s[tid] = c;
  }
  __syncthreads();
  if (tid == 0) {
    int s = 0;
    for (int t = 0; t < TT; ++t) { toff_s[t] = s; s += cnt_s[t]; }
    *nact = s;
  }
  __syncthreads();
  if (tid < TT) {
    int t = tid;
    int o = toff_s[t];
    int z = t * NB - o;            // inactive prefix count before t
    int c = cnt_s[t];
    for (int b = 0; b < NB; ++b) {
      int m = b * TT + t;
      if (b < c) trow_s[o + b] = m;
      else       zmap[z + (b - c)] = m;
    }
  }
  __syncthreads();
  int na = toff_s[TT - 1] + cnt_s[TT - 1];
  for (int k = tid; k < na; k += 256) trow[k] = trow_s[k];
  if (tid < 25) {
    int i = tid;
    if (i * 128 < na) {
      int k = min(i * 128 + 127, na - 1);
      tileneed[i] = (trow_s[k] % TT) + 2;   // Hsl[t] drained once flags >= t+2
    }
  }
}

// ---------------- combined prep: Wih | Winit | enc gather | X gather | Wfc ----
// One kernel, five index ranges (saves 4 launch gaps). Runs BEFORE the fused
// kernel on the full machine, so the 91MB Wfc conversion cannot congest the
// LSTM (r7 lesson: in-fused-kernel conversion burst cost ~26us).
__global__ __launch_bounds__(256) void prep_k(const float* __restrict__ w_ih,
                                              const float* __restrict__ wh,
                                              const float* __restrict__ wc,
                                              const float* __restrict__ enc,
                                              const float* __restrict__ emb,
                                              const float* __restrict__ w_fc,
                                              const int* __restrict__ caps,
                                              const int* __restrict__ sind,
                                              u16* __restrict__ Wih,
                                              u16* __restrict__ Winit,
                                              u16* __restrict__ Ebf,
                                              u16* __restrict__ Xb,
                                              u16* __restrict__ Wfc) {
  int i = blockIdx.x * 256 + threadIdx.x;
  const float* src;
  u16* dstp;
  if (i < 262144) {                       // Wih: [2048][512] f32 -> bf16
    src = w_ih + (size_t)i * 4;
    dstp = Wih + (size_t)i * 4;
  } else if (i < 786432) {                // Winit: concat rows -> [1024][2048]
    int e = (i - 262144) * 4;
    int row = e >> 11, col = e & 2047;
    src = (row < 512) ? (wh + (size_t)row * 2048 + col)
                      : (wc + (size_t)(row - 512) * 2048 + col);
    dstp = Winit + (size_t)(i - 262144) * 4;
  } else if (i < 819200) {                // enc gather: [64][2048]
    int e = (i - 786432) * 4;
    int r = e >> 11, k = e & 2047;
    src = enc + (size_t)sind[r] * ENCD + k;
    dstp = Ebf + (size_t)(i - 786432) * 4;
  } else if (i < 1228800) {               // X gather: [3200][512]
    int e = (i - 819200) * 4;
    int m = e >> 9, k = e & 511;
    unsigned b = ((unsigned)m * 5243u) >> 18;   // m/50
    int t = m - (int)b * TT;
    int cap = caps[sind[b] * LCAP + t];
    src = emb + (size_t)cap * EMB + k;
    dstp = Xb + (size_t)(i - 819200) * 4;
  } else if (i < 5068800) {               // Wfc: [30000][512] f32 -> bf16
    size_t idx = (size_t)(i - 1228800) * 4;
    src = w_fc + idx;
    dstp = Wfc + idx;
  } else return;
  float4 v = *(const float4*)src;
  ushort4 o;
  o.x = f2bf(v.x); o.y = f2bf(v.y); o.z = f2bf(v.z); o.w = f2bf(v.w);
  *(ushort4*)dstp = o;
}

// ---------------- bf16 MFMA GEMM: C[M][N] = A[M][K] * B[N][K]^T ----------------
// EPI 0: xW   -> out[row*Nr+col] = acc + bias0[col] + bias1[col]
// EPI 1: init -> col<512: h0 bf16 into outv in SLICE layout [j][b][8]; else c0 fp32
#define BM 128
#define BN 128
#define BK 32
#define LDT 40    // LDS row stride (bf16 elems); 2-way max bank aliasing

template <int EPI>
__global__ __launch_bounds__(256) void gemm_bt(const u16* __restrict__ A,
                                               const u16* __restrict__ Bm,
                                               int Mr, int Nr, int K,
                                               void* __restrict__ outv,
                                               float* __restrict__ out1,
                                               const float* __restrict__ bias0,
                                               const float* __restrict__ bias1) {
  __shared__ u16 As[BM * LDT];
  __shared__ u16 Bs[BN * LDT];
  int tid = threadIdx.x;
  int mBase = blockIdx.x * BM;
  int nBase = blockIdx.y * BN;

  int wid = tid >> 6, lane = tid & 63;
  int wm = (wid >> 1) * 64, wn = (wid & 1) * 64;
  int lm = lane & 15, lq = lane >> 4;

  f32x4 acc[4][4];
  for (int i = 0; i < 4; ++i)
    for (int j = 0; j < 4; ++j)
      acc[i][j] = (f32x4){0.f, 0.f, 0.f, 0.f};

  int nkt = K / BK;
  for (int kt = 0; kt < nkt; ++kt) {
    for (int it = 0; it < 2; ++it) {
      int li = tid + it * 256;       // 0..511
      int row = li >> 2, kq = li & 3;
      {
        int gr = min(mBase + row, Mr - 1);
        uint4 v = *(const uint4*)(A + (size_t)gr * K + kt * BK + kq * 8);
        *(uint4*)&As[row * LDT + kq * 8] = v;
      }
      {
        int gr = min(nBase + row, Nr - 1);
        uint4 v = *(const uint4*)(Bm + (size_t)gr * K + kt * BK + kq * 8);
        *(uint4*)&Bs[row * LDT + kq * 8] = v;
      }
    }
    __syncthreads();
    bf16x8 af[4], bfr[4];
    for (int i = 0; i < 4; ++i)
      af[i] = *(const bf16x8*)&As[(wm + i * 16 + lm) * LDT + lq * 8];
    for (int j = 0; j < 4; ++j)
      bfr[j] = *(const bf16x8*)&Bs[(wn + j * 16 + lm) * LDT + lq * 8];
    for (int i = 0; i < 4; ++i)
      for (int j = 0; j < 4; ++j)
        acc[i][j] = __builtin_amdgcn_mfma_f32_16x16x32_bf16(af[i], bfr[j], acc[i][j], 0, 0, 0);
    __syncthreads();
  }

  // epilogue: C row = (lane>>4)*4 + reg, col = lane&15
  for (int i = 0; i < 4; ++i) {
    int rloc0 = wm + i * 16 + (lane >> 4) * 4;
    for (int j = 0; j < 4; ++j) {
      int col = nBase + wn + j * 16 + (lane & 15);
      for (int r = 0; r < 4; ++r) {
        int rloc = rloc0 + r;
        float v = acc[i][j][r];
        if (EPI == 0) {
          int row = mBase + rloc;
          if (row < Mr && col < Nr)
            ((float*)outv)[(size_t)row * Nr + col] = v + bias0[col] + bias1[col];
        } else {
          int row = mBase + rloc;
          if (row < Mr && col < Nr) {
            if (col < 512) {
              // slice layout: h[j= col/8][batch=row][unit col%8] as u16
              int jj = col >> 3;
              ((u16*)outv)[(size_t)jj * 512 + row * 8 + (col & 7)] = f2bf(v + bias0[col]);
            } else {
              out1[(size_t)row * 512 + (col - 512)] = v + bias1[col - 512];
            }
          }
        }
      }
    }
  }
}

// ---------------- fused persistent LSTM + streaming FC ----------------
// Grid = 256 blocks x 256 threads, 1 block/CU. Blocks 0..63: LSTM (r2's
// verified 250us path, verbatim). Blocks 64..255 (F=192): FC consumers.
//
// Hs history layout (NEW this round): SLICE-major Hsl[t][j][b][8] u16.
// The LSTM's per-step history store becomes ONE contiguous 1KiB burst
// (16 full 64B lines) like its hx store, replacing 64 scattered 16B
// partial-line write-through transactions (4096/step GPU-wide) that sat on
// the producer drain path (next step's vmcnt(0) waits on them).
// FC A-staging: per-row u16 base = t*32768 + b*8 (precomputed in LDS);
// k-chunk kq reads 8 u16 at base + (kt*4+kq)*512 -- 16B aligned.
//
// FC job schedule (r7): nb-major contiguous chunks, XCD-swizzled, rt-outer.
// w_fc conversion moved back to prep_k (r7's in-kernel burst cost ~26us).
//
// FC readiness invariant (r5, verified): Hsl[t] (sc0sc1 write-through) is
// at the MALL once flags >= t+2; tail Hsl[49] covered by flag 51.
// Deadlock-free: dependencies flow only FC->LSTM; all poll thresholds <= 51
// and the final published flag is 51.
__global__ __launch_bounds__(256, 1) void lstm_fc(const float* __restrict__ w_hh,
                                                  const float* __restrict__ xW,
                                                  const float* __restrict__ cbuf,
                                                  u32* __restrict__ hx,
                                                  u32* __restrict__ Hs32,
                                                  int* __restrict__ flg,
                                                  const u16* __restrict__ Wfc,
                                                  const float* __restrict__ b_fc,
                                                  const int* __restrict__ trow,
                                                  const int* __restrict__ zmap,
                                                  const int* __restrict__ nactp,
                                                  const int* __restrict__ tileneed,
                                                  float* __restrict__ out) {
  __shared__ __align__(16) char smem[43520];
  int tid = threadIdx.x;
  int wave = tid >> 6, lane = tid & 63;
  int lm = lane & 15, lq = lane >> 4;

  if (blockIdx.x < 64) {
    // ================= LSTM block (r2/r5 verbatim, Hsl store updated) ======
    u16* wsm = (u16*)smem;                              // 32*520 u16 = 33280 B
    float* gsmf = (float*)(smem + 33280);               // 64*36 f32  = 9216 B
    u32* hsh = (u32*)(smem + 33280 + 9216);             // 256 u32    = 1024 B
#define GSM(rr, cc) gsmf[(rr) * 36 + (cc)]
    int j = blockIdx.x;
    int u0 = j * 8;

    // stage w_hh chunk (rows g*512+u0+ul, g=0..3, ul=0..7) -> wsm[g*8+ul][0..511]
    {
      int r = tid >> 3;              // 0..31
      int cc = (tid & 7) * 64;       // 64 floats per thread
      const float* src = w_hh + (size_t)((r >> 3) * HID + u0 + (r & 7)) * HID + cc;
      u16* dst = &wsm[r * 520 + cc];
#pragma unroll
      for (int q = 0; q < 16; ++q) {
        float4 v = ((const float4*)src)[q];
        ushort4 o; o.x = f2bf(v.x); o.y = f2bf(v.y); o.z = f2bf(v.z); o.w = f2bf(v.w);
        ((ushort4*)dst)[q] = o;
      }
    }
    __syncthreads();

    // time-invariant B fragments
    bf16x8 bfrag[2][16];
#pragma unroll
    for (int n = 0; n < 2; ++n)
#pragma unroll
      for (int kq = 0; kq < 16; ++kq)
        bfrag[n][kq] = *(const bf16x8*)&wsm[(n * 16 + lm) * 520 + kq * 32 + lq * 8];

    // pointwise mapping: thread owns (b = tid>>2, unit pair up = tid&3)
    int b = tid >> 2, up = tid & 3;
    float creg[2];
    {
      float2 c2 = *(const float2*)&cbuf[(size_t)b * HID + u0 + 2 * up];
      creg[0] = c2.x; creg[1] = c2.y;
    }

    // A-fragment base (dwords) in slice layout: slice (4*kq+lq), row (wave*16+lm)
    const int abase = lq * 256 + (wave * 16 + lm) * 4;

    for (int t = 0; t < TT; ++t) {
      const u32* hcur = hx + (size_t)(t & 1) * (NB * 256);
      u32* hnxt = hx + (size_t)((t + 1) & 1) * (NB * 256);

      // prefetch xW gate terms (independent of h; overlaps the poll)
      float xg[4][2];
      {
        const float* xwp = xW + (size_t)(b * TT + t) * G4 + u0 + 2 * up;
#pragma unroll
        for (int g = 0; g < 4; ++g) {
          float2 v = *(const float2*)&xwp[g * HID];
          xg[g][0] = v.x; xg[g][1] = v.y;
        }
      }

      // wait for h(t) complete at MALL: wave 0 only, single flag line
      if (t > 0) {
        if (wave == 0) poll_flags16<1>(flg, lane, (u32)t);
        __syncthreads();
      }

      // A fragments: wide cache-bypass loads straight from MALL (slice layout)
      u32x4 raw[16];
#pragma unroll
      for (int kq = 0; kq < 16; ++kq) {
        const u32* p = hcur + abase + kq * 1024;
        asm volatile("global_load_dwordx4 %0, %1, off sc0 sc1"
                     : "=v"(raw[kq]) : "v"(p) : "memory");
      }
      asm volatile("s_waitcnt vmcnt(0)"
                   : "+v"(raw[0]), "+v"(raw[1]), "+v"(raw[2]), "+v"(raw[3]),
                     "+v"(raw[4]), "+v"(raw[5]), "+v"(raw[6]), "+v"(raw[7]),
                     "+v"(raw[8]), "+v"(raw[9]), "+v"(raw[10]), "+v"(raw[11]),
                     "+v"(raw[12]), "+v"(raw[13]), "+v"(raw[14]), "+v"(raw[15])
                   :: "memory");

      f32x4 acc0 = (f32x4){0.f, 0.f, 0.f, 0.f};
      f32x4 acc1 = (f32x4){0.f, 0.f, 0.f, 0.f};
#pragma unroll
      for (int kq = 0; kq < 16; ++kq) {
        bf16x8 a = __builtin_bit_cast(bf16x8, raw[kq]);
        acc0 = __builtin_amdgcn_mfma_f32_16x16x32_bf16(a, bfrag[0][kq], acc0, 0, 0, 0);
        acc1 = __builtin_amdgcn_mfma_f32_16x16x32_bf16(a, bfrag[1][kq], acc1, 0, 0, 0);
      }
      // gsm redistribution is wave-local (wave w writes/reads rows [16w,16w+16))
#pragma unroll
      for (int r = 0; r < 4; ++r) {
        GSM(wave * 16 + lq * 4 + r, lm)      = acc0[r];
        GSM(wave * 16 + lq * 4 + r, 16 + lm) = acc1[r];
      }

      // pointwise: 2 adjacent units per thread -> pack one dword into LDS
      float hn2[2];
#pragma unroll
      for (int e = 0; e < 2; ++e) {
        int ul = 2 * up + e;
        float gi = GSM(b, ul)      + xg[0][e];
        float gf = GSM(b, 8 + ul)  + xg[1][e];
        float gg = GSM(b, 16 + ul) + xg[2][e];
        float go = GSM(b, 24 + ul) + xg[3][e];
        float cn = fast_sigmoid(gf) * creg[e] + fast_sigmoid(gi) * fast_tanh(gg);
        creg[e] = cn;
        hn2[e] = fast_sigmoid(go) * fast_tanh(cn);
      }
      hsh[b * 4 + up] = (u32)f2bf(hn2[0]) | ((u32)f2bf(hn2[1]) << 16);
      __syncthreads();   // hsh pack -> wave-0 store

      // wave 0: 1KiB hx slice store (sc0sc1) + drain + byte flag; Hsl history
      // store AFTER the flag, now ALSO one contiguous 1KiB burst (16 full
      // lines; drained by the NEXT step's vmcnt(0) -> flags>=t+2 invariant).
      if (tid < 64) {
        u32x4 hv = *(const u32x4*)&hsh[tid * 4];
        u32* dst = hnxt + j * 256 + tid * 4;
        asm volatile("global_store_dwordx4 %0, %1, off sc0 sc1"
                     :: "v"(dst), "v"(hv) : "memory");
        asm volatile("s_waitcnt vmcnt(0)" ::: "memory");
        if (tid == 0) {
          u32 fv = (u32)(t + 1);
          unsigned char* fj = (unsigned char*)flg + j;
          asm volatile("global_store_byte %0, %1, off sc0 sc1"
                       :: "v"(fj), "v"(fv) : "memory");
        }
        u32* hdst = Hs32 + (size_t)t * 16384 + j * 256 + tid * 4;
        asm volatile("global_store_dwordx4 %0, %1, off sc0 sc1"
                     :: "v"(hdst), "v"(hv) : "memory");
      }
    }
    // post-loop: drain wave-0's final Hsl store, publish flag 51 (covers t=49)
    if (wave == 0) {
      asm volatile("s_waitcnt vmcnt(0)" ::: "memory");
      if (lane == 0) {
        u32 fv = 51u;
        unsigned char* fj = (unsigned char*)flg + j;
        asm volatile("global_store_byte %0, %1, off sc0 sc1"
                     :: "v"(fj), "v"(fv) : "memory");
      }
    }
#undef GSM
  } else {
    // ================= FC consumer block =================
    u16* As = (u16*)smem;                    // 128*40 u16 = 10240 B
    u16* Bs = (u16*)(smem + 10240);          // 10240 B
    int* rmap_s = (int*)(smem + 20480);      // 512 B (out row m = b*50+t)
    int* hsl_s = (int*)(smem + 20992);       // 512 B (Hsl u16 base = t*32768+b*8)
    int* tn_s = (int*)(smem + 21504);        // 25 ints
    const u16* HsU = (const u16*)Hs32;       // Hsl[t][j][b][8] bf16

    if (tid < 25) tn_s[tid] = tileneed[tid];
    int nactv = nactp[0];
    int ntiles = (nactv + 127) >> 7;
    int totjobs = ntiles * 235;
    __syncthreads();

    const int F = 192;
    int f = blockIdx.x - 64;
    // XCD swizzle: blocks on XCD x get a CONTIGUOUS chunk range ->
    // contiguous Wfc panels resident in that XCD's L2.
    int fs = (f & 7) * 24 + (f >> 3);        // bijective on [0,192)
    int per = (totjobs + F - 1) / F;
    int J0 = fs * per;
    int J1 = min(J0 + per, totjobs);
    int wm = (wave >> 1) * 64, wn = (wave & 1) * 64;

    if (J0 < J1) {
      int p0 = J0 / ntiles, p1 = (J1 - 1) / ntiles;

      // rt-outer, panel-inner: flag needs ascend; per-rt work ~1.2 tiles.
      int lastNeed = 0;
      for (int rt = 0; rt < ntiles; ++rt) {
        int need = tn_s[rt];
        bool any = false;
        for (int p = p0; p <= p1; ++p) {
          int J = p * ntiles + rt;
          if (J >= J0 && J < J1) { any = true; break; }
        }
        if (!any) continue;
        if (need > lastNeed) {
          if (wave == 0) poll_flags16<64>(flg, lane, (u32)need);
          lastNeed = need;
        }
        __syncthreads();   // release after poll; fences rmap_s/LDS reuse
        if (tid < 128) {
          int k = (rt << 7) + tid;
          int m = trow[(k < nactv) ? k : (nactv - 1)];
          int bb = (m * 5243) >> 18;         // m/50 (m < 3200)
          int tt = m - bb * TT;
          rmap_s[tid] = m;
          hsl_s[tid] = tt * 32768 + bb * 8;  // u16 base into Hsl
        }
        __syncthreads();

        for (int p = p0; p <= p1; ++p) {
          int J = p * ntiles + rt;
          if (J < J0 || J >= J1) continue;
          int nBase = p * 128;

          f32x4 acc[4][4];
          for (int i = 0; i < 4; ++i)
            for (int jj = 0; jj < 4; ++jj)
              acc[i][jj] = (f32x4){0.f, 0.f, 0.f, 0.f};

          for (int kt = 0; kt < 16; ++kt) {
            for (int it = 0; it < 2; ++it) {
              int li = tid + it * 256;       // 0..511
              int row = li >> 2, kq = li & 3;
              {
                // Hsl: 8 u16 of j-slice (kt*4+kq) for this (b,t) row
                uint4 v = *(const uint4*)(HsU + (size_t)hsl_s[row] + (kt * 4 + kq) * 512);
                *(uint4*)&As[row * LDT + kq * 8] = v;
              }
              {
                int gb = min(nBase + row, VOC - 1);
                uint4 v = *(const uint4*)(Wfc + (size_t)gb * 512 + kt * BK + kq * 8);
                *(uint4*)&Bs[row * LDT + kq * 8] = v;
              }
            }
            __syncthreads();
            bf16x8 af[4], bfr[4];
            for (int i = 0; i < 4; ++i)
              af[i] = *(const bf16x8*)&As[(wm + i * 16 + lm) * LDT + lq * 8];
            for (int jj = 0; jj < 4; ++jj)
              bfr[jj] = *(const bf16x8*)&Bs[(wn + jj * 16 + lm) * LDT + lq * 8];
            for (int i = 0; i < 4; ++i)
              for (int jj = 0; jj < 4; ++jj)
                acc[i][jj] = __builtin_amdgcn_mfma_f32_16x16x32_bf16(af[i], bfr[jj], acc[i][jj], 0, 0, 0);
            __syncthreads();
          }

          // epilogue: output row = rmap_s[rloc] (padding duplicates last
          // active row -> duplicate same-value writes, benign)
          for (int i = 0; i < 4; ++i) {
            int rloc0 = wm + i * 16 + lq * 4;
            for (int jj = 0; jj < 4; ++jj) {
              int col = nBase + wn + jj * 16 + lm;
              if (col < VOC) {
                float bias = b_fc[col];
                for (int r = 0; r < 4; ++r) {
                  int m = rmap_s[rloc0 + r];
                  out[(size_t)m * VOC + col] = acc[i][jj][r] + bias;
                }
              }
            }
          }
        }
      }
    }

    // zero-fill masked rows AFTER the gated loop (lands at/after LSTM end,
    // cannot congest the running LSTM).
    int nz = NB * TT - nactv;
    float4 zz = {0.f, 0.f, 0.f, 0.f};
    for (int r = f; r < nz; r += F) {
      float4* dst = (float4*)(out + (size_t)zmap[r] * VOC);
      for (int c4 = tid; c4 < VOC / 4; c4 += 256) dst[c4] = zz;
    }
  }
}

// ---------------- launcher ----------------
extern "C" void kernel_launch(void* const* d_in, const int* in_sizes, int n_in,
                              void* d_out, int out_size, void* d_ws, size_t ws_size,
                              hipStream_t stream) {
  const float* encoder_out = (const float*)d_in[0];
  const int*   caps        = (const int*)d_in[1];
  const int*   cap_len     = (const int*)d_in[2];
  const float* emb         = (const float*)d_in[3];
  const float* w_ih        = (const float*)d_in[4];
  const float* b_ih        = (const float*)d_in[5];
  const float* w_hh        = (const float*)d_in[6];
  const float* b_hh        = (const float*)d_in[7];
  const float* w_init_h    = (const float*)d_in[8];
  const float* b_init_h    = (const float*)d_in[9];
  const float* w_init_c    = (const float*)d_in[10];
  const float* b_init_c    = (const float*)d_in[11];
  const float* w_fc        = (const float*)d_in[12];
  const float* b_fc        = (const float*)d_in[13];
  float* out = (float*)d_out;

  char* ws = (char*)d_ws;
  int*   sind    = (int*)(ws + 0);          // 256 B
  int*   dlen    = (int*)(ws + 256);        // 256 B
  int*   nact    = (int*)(ws + 512);        // 64 B
  int*   flags   = (int*)(ws + 576);        // 64 B byte-flag line
  int*   tilend  = (int*)(ws + 640);        // 100 B (25 ints)
  int*   trow    = (int*)(ws + 832);        // 12800 B (t-major active rows)
  int*   zmap    = (int*)(ws + 13632);      // 12800 B (inactive rows)
  float* cbuf    = (float*)(ws + 26496);    // 64*512*4 = 131072
  u16*   hbuf    = (u16*)(ws + 157568);     // 2*64*512*2 = 131072 (hx ping-pong, slice layout)
  float* xW      = (float*)(ws + 288640);   // 3200*2048*4 = 26214400
  u16*   Hs      = (u16*)(ws + 26503040);   // Hsl[50][64][64][8] = 3276800 B
  u16*   Xb      = (u16*)(ws + 29779840);   // 3276800
  u16*   Wih     = (u16*)(ws + 33056640);   // 2097152
  u16*   Winit   = (u16*)(ws + 35153792);   // 4194304
  u16*   Wfc     = (u16*)(ws + 39348096);   // 30720000
  u16*   Ebf     = (u16*)(ws + 70068096);   // 262144  -> end 70330240

  sort_k<<<1, 256, 0, stream>>>(cap_len, caps, out, sind, dlen, trow, zmap,
                                nact, flags, tilend);
  // combined converts/gathers + Wfc: 5068800 float4-units / 256 = 19800 blocks
  prep_k<<<19800, 256, 0, stream>>>(w_ih, w_init_h, w_init_c, encoder_out,
                                    emb, w_fc, caps, sind,
                                    Wih, Winit, Ebf, Xb, Wfc);

  // h0 (bf16, slice layout, into hx buffer 0) | c0 (fp32)
  gemm_bt<1><<<dim3(1, 8), 256, 0, stream>>>(Ebf, Winit, 64, 1024, 2048,
                                             hbuf, cbuf, b_init_h, b_init_c);
  // xW = X @ w_ih^T + b_ih + b_hh  (all steps at once)
  gemm_bt<0><<<dim3(25, 16), 256, 0, stream>>>(Xb, Wih, 3200, 2048, 512,
                                               xW, nullptr, b_ih, b_hh);
  // fused: 50 LSTM steps (64 blocks) + panel-resident streaming FC (192 blocks)
  lstm_fc<<<256, 256, 0, stream>>>(w_hh, xW, cbuf, (u32*)hbuf, (u32*)Hs, flags,
                                   Wfc, b_fc, trow, zmap, nact, tilend, out);
}

// Round 9
// 807.998 us; speedup vs baseline: 1.1160x; 1.1160x over previous
//
#include <hip/hip_runtime.h>

// Problem constants
#define NB    64      // batch
#define LCAP  51      // caption length
#define TT    50      // decode steps
#define HID   512
#define EMB   512
#define VOC   30000
#define ENCD  2048
#define G4    2048    // 4*HID

typedef unsigned short u16;
typedef unsigned int   u32;
typedef __attribute__((ext_vector_type(8))) short bf16x8;
typedef __attribute__((ext_vector_type(4))) float f32x4;
typedef __attribute__((ext_vector_type(4))) unsigned int u32x4;

__device__ __forceinline__ u16 f2bf(float x) {
  union { float f; unsigned u; } v; v.f = x;
  unsigned r = v.u + 0x7fffu + ((v.u >> 16) & 1u);
  return (u16)(r >> 16);
}

__device__ __forceinline__ float fast_sigmoid(float x) {
  return 1.f / (1.f + __expf(-x));
}
__device__ __forceinline__ float fast_tanh(float x) {
  float xx = fminf(fmaxf(x, -10.f), 10.f);
  float e = __expf(2.f * xx);
  return (e - 1.f) * __frcp_rn(e + 1.f);
}

// 16-lane poll over the single 64B byte-flag line: wait until all 64 byte
// flags >= tt. One line-request per block per iteration.
// SLEEP: latency-critical LSTM pollers use 1 (~64cy); FC pollers use 64
// (~1.7us) -- r1/r4 proved fast polling from many blocks congests the MALL.
template <int SLEEP>
__device__ __forceinline__ void poll_flags16(const int* flg, int lane, u32 tt) {
  if (lane < 16) {
    const u32* myp = (const u32*)flg + lane;
    u32 f;
    for (;;) {
      asm volatile("global_load_dword %0, %1, off sc0 sc1"
                   : "=v"(f) : "v"(myp) : "memory");
      asm volatile("s_waitcnt vmcnt(0)" : "+v"(f) :: "memory");
      if (((f & 0xffu) >= tt) & (((f >> 8) & 0xffu) >= tt) &
          (((f >> 16) & 0xffu) >= tt) & ((f >> 24) >= tt)) break;
      __builtin_amdgcn_s_sleep(SLEEP);
    }
  }
}

// ---------------- sort + int outputs + t-major compaction + flag init ----------------
// Flag protocol (shifted +1 this round for in-kernel h0):
//   flag = 1        : h0 stored (the "step -1" round)
//   flag = t+2      : step t done (h(t+1) stored+drained)
//   flag = 52       : post-loop (Hs[49] drained)
// Hs[.,t] is drained once flags >= t+3  ->  tileneed = t_last + 3 (uniform).
__global__ __launch_bounds__(256) void sort_k(const int* __restrict__ cap_len,
                                              const int* __restrict__ caps,
                                              float* __restrict__ out,
                                              int* __restrict__ sind,
                                              int* __restrict__ dlen,
                                              int* __restrict__ trow,
                                              int* __restrict__ zmap,
                                              int* __restrict__ nact,
                                              int* __restrict__ flags,
                                              int* __restrict__ tileneed) {
  __shared__ int smlen[NB];
  __shared__ int smpos[NB];
  __shared__ int sdl[NB];
  __shared__ int cnt_s[TT];
  __shared__ int toff_s[TT];
  __shared__ int trow_s[NB * TT];
  int tid = threadIdx.x;
  if (tid < NB) { smlen[tid] = cap_len[tid]; flags[tid] = 0; }
  __syncthreads();
  if (tid < NB) {
    int li = smlen[tid];
    int rank = 0;
    for (int j = 0; j < NB; ++j) {
      int lj = smlen[j];
      rank += (lj > li || (lj == li && j < tid)) ? 1 : 0;
    }
    smpos[rank] = tid;
  }
  __syncthreads();
  if (tid < NB) {
    int src = smpos[tid];
    int dl = smlen[src] - 1;
    sind[tid] = src;
    dlen[tid] = dl;
    sdl[tid] = dl;
    float* caps_out = out + (size_t)NB * TT * VOC;          // 96,000,000
    for (int l = 0; l < LCAP; ++l)
      caps_out[tid * LCAP + l] = (float)caps[src * LCAP + l];
    out[96003264 + tid] = (float)dl;       // dec_len
    out[96003328 + tid] = (float)src;      // sort_ind
  }
  __syncthreads();
  if (tid < TT) {
    int c = 0;
    for (int b = 0; b < NB; ++b) c += (sdl[b] > tid) ? 1 : 0;
    cnt_s[tid] = c;
  }
  __syncthreads();
  if (tid == 0) {
    int s = 0;
    for (int t = 0; t < TT; ++t) { toff_s[t] = s; s += cnt_s[t]; }
    *nact = s;
  }
  __syncthreads();
  if (tid < TT) {
    int t = tid;
    int o = toff_s[t];
    int z = t * NB - o;            // inactive prefix count before t
    int c = cnt_s[t];
    for (int b = 0; b < NB; ++b) {
      int m = b * TT + t;
      if (b < c) trow_s[o + b] = m;
      else       zmap[z + (b - c)] = m;
    }
  }
  __syncthreads();
  int na = toff_s[TT - 1] + cnt_s[TT - 1];
  for (int k = tid; k < na; k += 256) trow[k] = trow_s[k];
  if (tid < 25) {
    int i = tid;
    if (i * 128 < na) {
      int k = min(i * 128 + 127, na - 1);
      tileneed[i] = (trow_s[k] % TT) + 3;   // shifted protocol: Hs[t] at flags>=t+3
    }
  }
}

// ---------------- combined prep: Wih | enc gather | X gather | Wfc ----------
// One kernel, four index ranges. Winit range removed: h0/c0 are now computed
// inside the LSTM blocks from Ebf + w_init_{h,c} directly.
__global__ __launch_bounds__(256) void prep_k(const float* __restrict__ w_ih,
                                              const float* __restrict__ enc,
                                              const float* __restrict__ emb,
                                              const float* __restrict__ w_fc,
                                              const int* __restrict__ caps,
                                              const int* __restrict__ sind,
                                              u16* __restrict__ Wih,
                                              u16* __restrict__ Ebf,
                                              u16* __restrict__ Xb,
                                              u16* __restrict__ Wfc) {
  int i = blockIdx.x * 256 + threadIdx.x;
  const float* src;
  u16* dstp;
  if (i < 262144) {                       // Wih: [2048][512] f32 -> bf16
    src = w_ih + (size_t)i * 4;
    dstp = Wih + (size_t)i * 4;
  } else if (i < 294912) {                // enc gather: [64][2048]
    int e = (i - 262144) * 4;
    int r = e >> 11, k = e & 2047;
    src = enc + (size_t)sind[r] * ENCD + k;
    dstp = Ebf + (size_t)(i - 262144) * 4;
  } else if (i < 704512) {                // X gather: [3200][512]
    int e = (i - 294912) * 4;
    int m = e >> 9, k = e & 511;
    unsigned b = ((unsigned)m * 5243u) >> 18;   // m/50
    int t = m - (int)b * TT;
    int cap = caps[sind[b] * LCAP + t];
    src = emb + (size_t)cap * EMB + k;
    dstp = Xb + (size_t)(i - 294912) * 4;
  } else if (i < 4544512) {               // Wfc: [30000][512] f32 -> bf16
    size_t idx = (size_t)(i - 704512) * 4;
    src = w_fc + idx;
    dstp = Wfc + idx;
  } else return;
  float4 v = *(const float4*)src;
  ushort4 o;
  o.x = f2bf(v.x); o.y = f2bf(v.y); o.z = f2bf(v.z); o.w = f2bf(v.w);
  *(ushort4*)dstp = o;
}

// ---------------- bf16 MFMA GEMM (xW only): C = A[M][K] * B[N][K]^T + b0 + b1 ----
#define BM 128
#define BN 128
#define BK 32
#define LDT 40    // LDS row stride (bf16 elems); 2-way max bank aliasing

__global__ __launch_bounds__(256) void gemm_bt(const u16* __restrict__ A,
                                               const u16* __restrict__ Bm,
                                               int Mr, int Nr, int K,
                                               float* __restrict__ outv,
                                               const float* __restrict__ bias0,
                                               const float* __restrict__ bias1) {
  __shared__ u16 As[BM * LDT];
  __shared__ u16 Bs[BN * LDT];
  int tid = threadIdx.x;
  int mBase = blockIdx.x * BM;
  int nBase = blockIdx.y * BN;

  int wid = tid >> 6, lane = tid & 63;
  int wm = (wid >> 1) * 64, wn = (wid & 1) * 64;
  int lm = lane & 15, lq = lane >> 4;

  f32x4 acc[4][4];
  for (int i = 0; i < 4; ++i)
    for (int j = 0; j < 4; ++j)
      acc[i][j] = (f32x4){0.f, 0.f, 0.f, 0.f};

  int nkt = K / BK;
  for (int kt = 0; kt < nkt; ++kt) {
    for (int it = 0; it < 2; ++it) {
      int li = tid + it * 256;       // 0..511
      int row = li >> 2, kq = li & 3;
      {
        int gr = min(mBase + row, Mr - 1);
        uint4 v = *(const uint4*)(A + (size_t)gr * K + kt * BK + kq * 8);
        *(uint4*)&As[row * LDT + kq * 8] = v;
      }
      {
        int gr = min(nBase + row, Nr - 1);
        uint4 v = *(const uint4*)(Bm + (size_t)gr * K + kt * BK + kq * 8);
        *(uint4*)&Bs[row * LDT + kq * 8] = v;
      }
    }
    __syncthreads();
    bf16x8 af[4], bfr[4];
    for (int i = 0; i < 4; ++i)
      af[i] = *(const bf16x8*)&As[(wm + i * 16 + lm) * LDT + lq * 8];
    for (int j = 0; j < 4; ++j)
      bfr[j] = *(const bf16x8*)&Bs[(wn + j * 16 + lm) * LDT + lq * 8];
    for (int i = 0; i < 4; ++i)
      for (int j = 0; j < 4; ++j)
        acc[i][j] = __builtin_amdgcn_mfma_f32_16x16x32_bf16(af[i], bfr[j], acc[i][j], 0, 0, 0);
    __syncthreads();
  }

  for (int i = 0; i < 4; ++i) {
    int rloc0 = wm + i * 16 + (lane >> 4) * 4;
    for (int j = 0; j < 4; ++j) {
      int col = nBase + wn + j * 16 + (lane & 15);
      for (int r = 0; r < 4; ++r) {
        int row = mBase + rloc0 + r;
        if (row < Mr && col < Nr)
          outv[(size_t)row * Nr + col] = acc[i][j][r] + bias0[col] + bias1[col];
      }
    }
  }
}

// ---------------- fused persistent LSTM + streaming FC ----------------
// Grid = 256 blocks x 256 threads, 1 block/CU. Blocks 0..63: LSTM. Blocks
// 64..255 (F=192): FC consumers (r5's verified 370us structure: row-major
// Hs[m][512], rt-major round-robin jobs -- r8's Hsl scatter layout reverted).
//
// NEW this round: h0/c0 computed IN-KERNEL by each LSTM block (replaces the
// 8-block gemm_bt<1> dispatch that burned ~43us+gap on a 2.7us GEMM). Block
// j needs only its own 8-unit slice: per wave one 16x16x32 MFMA chain over
// K=2048 with B = [8 w_init_h rows | 8 w_init_c rows] -> one accumulator
// yields both h0 (cols 0..7) and c0 (cols 8..15). c0 -> creg directly
// (wave-local gsm redistribution, same argument as the main loop); h0 goes
// through the existing hsh -> hx[buf0] store + flag as a "step -1" round.
//
// Flag protocol (shifted +1): h0 stored -> flag 1; step t polls flags>=t+1,
// stores h(t+1), sets flag t+2; post-loop flag 52. FC: Hs[.,t] drained once
// flags >= t+3 (uniform, incl. tail 49+3=52). Deadlock-free: deps flow only
// FC->LSTM; all poll thresholds <= 52 = final flag.
__global__ __launch_bounds__(256, 1) void lstm_fc(const float* __restrict__ w_hh,
                                                  const float* __restrict__ w_init_h,
                                                  const float* __restrict__ w_init_c,
                                                  const float* __restrict__ b_init_h,
                                                  const float* __restrict__ b_init_c,
                                                  const u16* __restrict__ Ebf,
                                                  const float* __restrict__ xW,
                                                  u32* __restrict__ hx,
                                                  u32* __restrict__ Hs32,
                                                  int* __restrict__ flg,
                                                  const u16* __restrict__ Wfc,
                                                  const float* __restrict__ b_fc,
                                                  const int* __restrict__ trow,
                                                  const int* __restrict__ zmap,
                                                  const int* __restrict__ nactp,
                                                  const int* __restrict__ tileneed,
                                                  float* __restrict__ out) {
  __shared__ __align__(16) char smem[43520];
  int tid = threadIdx.x;
  int wave = tid >> 6, lane = tid & 63;
  int lm = lane & 15, lq = lane >> 4;

  if (blockIdx.x < 64) {
    // ================= LSTM block =================
    u16* wsm = (u16*)smem;                              // 32*520 u16 = 33280 B
    float* gsmf = (float*)(smem + 33280);               // 64*36 f32  = 9216 B
    u32* hsh = (u32*)(smem + 33280 + 9216);             // 256 u32    = 1024 B
#define GSM(rr, cc) gsmf[(rr) * 36 + (cc)]
    int j = blockIdx.x;
    int u0 = j * 8;

    // stage w_hh chunk (rows g*512+u0+ul, g=0..3, ul=0..7) -> wsm[g*8+ul][0..511]
    {
      int r = tid >> 3;              // 0..31
      int cc = (tid & 7) * 64;       // 64 floats per thread
      const float* src = w_hh + (size_t)((r >> 3) * HID + u0 + (r & 7)) * HID + cc;
      u16* dst = &wsm[r * 520 + cc];
#pragma unroll
      for (int q = 0; q < 16; ++q) {
        float4 v = ((const float4*)src)[q];
        ushort4 o; o.x = f2bf(v.x); o.y = f2bf(v.y); o.z = f2bf(v.z); o.w = f2bf(v.w);
        ((ushort4*)dst)[q] = o;
      }
    }
    __syncthreads();

    // time-invariant B fragments
    bf16x8 bfrag[2][16];
#pragma unroll
    for (int n = 0; n < 2; ++n)
#pragma unroll
      for (int kq = 0; kq < 16; ++kq)
        bfrag[n][kq] = *(const bf16x8*)&wsm[(n * 16 + lm) * 520 + kq * 32 + lq * 8];

    // pointwise mapping: thread owns (b = tid>>2, unit pair up = tid&3)
    int b = tid >> 2, up = tid & 3;
    float creg[2];

    // ---- in-kernel h0/c0: C[batch][0:8]=h0 slice, [8:16]=c0 slice, K=2048 ----
    {
      f32x4 iacc = (f32x4){0.f, 0.f, 0.f, 0.f};
      const u16* aptr = Ebf + (size_t)(wave * 16 + lm) * 2048;
      const float* wsrc = (lm < 8) ? (w_init_h + (size_t)(u0 + lm) * 2048)
                                   : (w_init_c + (size_t)(u0 + (lm - 8)) * 2048);
#pragma unroll 4
      for (int kt = 0; kt < 64; ++kt) {
        int ko = kt * 32 + lq * 8;
        bf16x8 a = *(const bf16x8*)(aptr + ko);
        float4 b0 = *(const float4*)(wsrc + ko);
        float4 b1 = *(const float4*)(wsrc + ko + 4);
        bf16x8 bfv;
        bfv[0] = (short)f2bf(b0.x); bfv[1] = (short)f2bf(b0.y);
        bfv[2] = (short)f2bf(b0.z); bfv[3] = (short)f2bf(b0.w);
        bfv[4] = (short)f2bf(b1.x); bfv[5] = (short)f2bf(b1.y);
        bfv[6] = (short)f2bf(b1.z); bfv[7] = (short)f2bf(b1.w);
        iacc = __builtin_amdgcn_mfma_f32_16x16x32_bf16(a, bfv, iacc, 0, 0, 0);
      }
      float ibias = (lm < 8) ? b_init_h[u0 + lm] : b_init_c[u0 + (lm - 8)];
#pragma unroll
      for (int r = 0; r < 4; ++r)
        GSM(wave * 16 + lq * 4 + r, lm) = iacc[r] + ibias;
      // wave-local redistribution (writer wave of batch b == reader wave:
      // writer wave = b>>4; reader thread 4b+up is in wave (4b+up)>>6 = b>>4)
      creg[0] = GSM(b, 8 + 2 * up);
      creg[1] = GSM(b, 8 + 2 * up + 1);
      float h00 = GSM(b, 2 * up), h01 = GSM(b, 2 * up + 1);
      hsh[b * 4 + up] = (u32)f2bf(h00) | ((u32)f2bf(h01) << 16);
      __syncthreads();   // hsh pack -> wave-0 store
      if (tid < 64) {
        u32x4 hv = *(const u32x4*)&hsh[tid * 4];
        u32* dst = hx + j * 256 + tid * 4;     // ping-pong buffer 0
        asm volatile("global_store_dwordx4 %0, %1, off sc0 sc1"
                     :: "v"(dst), "v"(hv) : "memory");
        asm volatile("s_waitcnt vmcnt(0)" ::: "memory");
        if (tid == 0) {
          u32 fv = 1u;
          unsigned char* fj = (unsigned char*)flg + j;
          asm volatile("global_store_byte %0, %1, off sc0 sc1"
                       :: "v"(fj), "v"(fv) : "memory");
        }
      }
    }

    // A-fragment base (dwords) in slice layout: slice (4*kq+lq), row (wave*16+lm)
    const int abase = lq * 256 + (wave * 16 + lm) * 4;

    for (int t = 0; t < TT; ++t) {
      const u32* hcur = hx + (size_t)(t & 1) * (NB * 256);
      u32* hnxt = hx + (size_t)((t + 1) & 1) * (NB * 256);

      // prefetch xW gate terms (independent of h; overlaps the poll)
      float xg[4][2];
      {
        const float* xwp = xW + (size_t)(b * TT + t) * G4 + u0 + 2 * up;
#pragma unroll
        for (int g = 0; g < 4; ++g) {
          float2 v = *(const float2*)&xwp[g * HID];
          xg[g][0] = v.x; xg[g][1] = v.y;
        }
      }

      // wait for h(t) at MALL (flag t+1): wave 0 only, single flag line
      if (wave == 0) poll_flags16<1>(flg, lane, (u32)(t + 1));
      __syncthreads();

      // A fragments: wide cache-bypass loads straight from MALL (slice layout)
      u32x4 raw[16];
#pragma unroll
      for (int kq = 0; kq < 16; ++kq) {
        const u32* p = hcur + abase + kq * 1024;
        asm volatile("global_load_dwordx4 %0, %1, off sc0 sc1"
                     : "=v"(raw[kq]) : "v"(p) : "memory");
      }
      asm volatile("s_waitcnt vmcnt(0)"
                   : "+v"(raw[0]), "+v"(raw[1]), "+v"(raw[2]), "+v"(raw[3]),
                     "+v"(raw[4]), "+v"(raw[5]), "+v"(raw[6]), "+v"(raw[7]),
                     "+v"(raw[8]), "+v"(raw[9]), "+v"(raw[10]), "+v"(raw[11]),
                     "+v"(raw[12]), "+v"(raw[13]), "+v"(raw[14]), "+v"(raw[15])
                   :: "memory");

      f32x4 acc0 = (f32x4){0.f, 0.f, 0.f, 0.f};
      f32x4 acc1 = (f32x4){0.f, 0.f, 0.f, 0.f};
#pragma unroll
      for (int kq = 0; kq < 16; ++kq) {
        bf16x8 a = __builtin_bit_cast(bf16x8, raw[kq]);
        acc0 = __builtin_amdgcn_mfma_f32_16x16x32_bf16(a, bfrag[0][kq], acc0, 0, 0, 0);
        acc1 = __builtin_amdgcn_mfma_f32_16x16x32_bf16(a, bfrag[1][kq], acc1, 0, 0, 0);
      }
      // gsm redistribution is wave-local (wave w writes/reads rows [16w,16w+16))
#pragma unroll
      for (int r = 0; r < 4; ++r) {
        GSM(wave * 16 + lq * 4 + r, lm)      = acc0[r];
        GSM(wave * 16 + lq * 4 + r, 16 + lm) = acc1[r];
      }

      // pointwise: 2 adjacent units per thread -> pack one dword into LDS
      float hn2[2];
#pragma unroll
      for (int e = 0; e < 2; ++e) {
        int ul = 2 * up + e;
        float gi = GSM(b, ul)      + xg[0][e];
        float gf = GSM(b, 8 + ul)  + xg[1][e];
        float gg = GSM(b, 16 + ul) + xg[2][e];
        float go = GSM(b, 24 + ul) + xg[3][e];
        float cn = fast_sigmoid(gf) * creg[e] + fast_sigmoid(gi) * fast_tanh(gg);
        creg[e] = cn;
        hn2[e] = fast_sigmoid(go) * fast_tanh(cn);
      }
      hsh[b * 4 + up] = (u32)f2bf(hn2[0]) | ((u32)f2bf(hn2[1]) << 16);
      __syncthreads();   // hsh pack -> wave-0 store

      // wave 0: 1KiB hx slice store (sc0sc1) + drain + byte flag (t+2); Hs
      // history store AFTER the flag (row-major Hs[m][512]; drained by the
      // NEXT step's vmcnt(0) -> flags>=t+3 readiness invariant).
      if (tid < 64) {
        u32x4 hv = *(const u32x4*)&hsh[tid * 4];
        u32* dst = hnxt + j * 256 + tid * 4;
        asm volatile("global_store_dwordx4 %0, %1, off sc0 sc1"
                     :: "v"(dst), "v"(hv) : "memory");
        asm volatile("s_waitcnt vmcnt(0)" ::: "memory");
        if (tid == 0) {
          u32 fv = (u32)(t + 2);
          unsigned char* fj = (unsigned char*)flg + j;
          asm volatile("global_store_byte %0, %1, off sc0 sc1"
                       :: "v"(fj), "v"(fv) : "memory");
        }
        u32* hdst = Hs32 + ((size_t)tid * TT + t) * 256 + j * 4;
        asm volatile("global_store_dwordx4 %0, %1, off sc0 sc1"
                     :: "v"(hdst), "v"(hv) : "memory");
      }
    }
    // post-loop: drain wave-0's final Hs store, publish flag 52 (covers t=49)
    if (wave == 0) {
      asm volatile("s_waitcnt vmcnt(0)" ::: "memory");
      if (lane == 0) {
        u32 fv = 52u;
        unsigned char* fj = (unsigned char*)flg + j;
        asm volatile("global_store_byte %0, %1, off sc0 sc1"
                     :: "v"(fj), "v"(fv) : "memory");
      }
    }
#undef GSM
  } else {
    // ================= FC consumer block (r5 verbatim) =================
    u16* As = (u16*)smem;                    // 128*40 u16 = 10240 B
    u16* Bs = (u16*)(smem + 10240);          // 10240 B
    int* rmap_s = (int*)(smem + 20480);      // 512 B
    int* tn_s = (int*)(smem + 20992);        // 25 ints
    const u16* HsA = (const u16*)Hs32;       // [3200][512] bf16 (row m = b*50+t)

    if (tid < 25) tn_s[tid] = tileneed[tid];
    int nactv = nactp[0];
    int ntiles = (nactv + 127) >> 7;
    int totjobs = ntiles * 235;
    __syncthreads();

    const int F = 192;
    int f = blockIdx.x - 64;
    int wm = (wave >> 1) * 64, wn = (wave & 1) * 64;

    int lastNeed = 0;
    for (int job = f; job < totjobs; job += F) {
      int rt = job / 235;
      int nb = job - rt * 235;
      int nBase = nb * 128;
      int need = tn_s[rt];
      if (need > lastNeed) {
        if (wave == 0) poll_flags16<64>(flg, lane, (u32)need);
        lastNeed = need;
      }
      __syncthreads();   // release after poll; also fences rmap_s/LDS reuse
      if (tid < 128) {
        int k = (rt << 7) + tid;
        rmap_s[tid] = trow[(k < nactv) ? k : (nactv - 1)];
      }
      __syncthreads();

      f32x4 acc[4][4];
      for (int i = 0; i < 4; ++i)
        for (int jj = 0; jj < 4; ++jj)
          acc[i][jj] = (f32x4){0.f, 0.f, 0.f, 0.f};

      for (int kt = 0; kt < 16; ++kt) {
        for (int it = 0; it < 2; ++it) {
          int li = tid + it * 256;       // 0..511
          int row = li >> 2, kq = li & 3;
          {
            int gr = rmap_s[row];
            uint4 v = *(const uint4*)(HsA + (size_t)gr * 512 + kt * BK + kq * 8);
            *(uint4*)&As[row * LDT + kq * 8] = v;
          }
          {
            int gb = min(nBase + row, VOC - 1);
            uint4 v = *(const uint4*)(Wfc + (size_t)gb * 512 + kt * BK + kq * 8);
            *(uint4*)&Bs[row * LDT + kq * 8] = v;
          }
        }
        __syncthreads();
        bf16x8 af[4], bfr[4];
        for (int i = 0; i < 4; ++i)
          af[i] = *(const bf16x8*)&As[(wm + i * 16 + lm) * LDT + lq * 8];
        for (int jj = 0; jj < 4; ++jj)
          bfr[jj] = *(const bf16x8*)&Bs[(wn + jj * 16 + lm) * LDT + lq * 8];
        for (int i = 0; i < 4; ++i)
          for (int jj = 0; jj < 4; ++jj)
            acc[i][jj] = __builtin_amdgcn_mfma_f32_16x16x32_bf16(af[i], bfr[jj], acc[i][jj], 0, 0, 0);
        __syncthreads();
      }

      // epilogue: output row = rmap_s[rloc] (padding duplicates last active
      // row -> duplicate same-value writes, benign)
      for (int i = 0; i < 4; ++i) {
        int rloc0 = wm + i * 16 + lq * 4;
        for (int jj = 0; jj < 4; ++jj) {
          int col = nBase + wn + jj * 16 + lm;
          if (col < VOC) {
            float bias = b_fc[col];
            for (int r = 0; r < 4; ++r) {
              int m = rmap_s[rloc0 + r];
              out[(size_t)m * VOC + col] = acc[i][jj][r] + bias;
            }
          }
        }
      }
    }

    // zero-fill masked rows AFTER the gated loop (lands at/after LSTM end,
    // cannot congest the running LSTM).
    int nz = NB * TT - nactv;
    float4 zz = {0.f, 0.f, 0.f, 0.f};
    for (int r = f; r < nz; r += F) {
      float4* dst = (float4*)(out + (size_t)zmap[r] * VOC);
      for (int c4 = tid; c4 < VOC / 4; c4 += 256) dst[c4] = zz;
    }
  }
}

// ---------------- launcher ----------------
extern "C" void kernel_launch(void* const* d_in, const int* in_sizes, int n_in,
                              void* d_out, int out_size, void* d_ws, size_t ws_size,
                              hipStream_t stream) {
  const float* encoder_out = (const float*)d_in[0];
  const int*   caps        = (const int*)d_in[1];
  const int*   cap_len     = (const int*)d_in[2];
  const float* emb         = (const float*)d_in[3];
  const float* w_ih        = (const float*)d_in[4];
  const float* b_ih        = (const float*)d_in[5];
  const float* w_hh        = (const float*)d_in[6];
  const float* b_hh        = (const float*)d_in[7];
  const float* w_init_h    = (const float*)d_in[8];
  const float* b_init_h    = (const float*)d_in[9];
  const float* w_init_c    = (const float*)d_in[10];
  const float* b_init_c    = (const float*)d_in[11];
  const float* w_fc        = (const float*)d_in[12];
  const float* b_fc        = (const float*)d_in[13];
  float* out = (float*)d_out;

  char* ws = (char*)d_ws;
  int*   sind    = (int*)(ws + 0);          // 256 B
  int*   dlen    = (int*)(ws + 256);        // 256 B
  int*   nact    = (int*)(ws + 512);        // 64 B
  int*   flags   = (int*)(ws + 576);        // 64 B byte-flag line
  int*   tilend  = (int*)(ws + 640);        // 100 B (25 ints)
  int*   trow    = (int*)(ws + 832);        // 12800 B (t-major active rows)
  int*   zmap    = (int*)(ws + 13632);      // 12800 B (inactive rows)
  u16*   hbuf    = (u16*)(ws + 157568);     // 2*64*512*2 = 131072 (hx ping-pong, slice layout)
  float* xW      = (float*)(ws + 288640);   // 3200*2048*4 = 26214400
  u16*   Hs      = (u16*)(ws + 26503040);   // 3200*512*2 = 3276800 (row-major)
  u16*   Xb      = (u16*)(ws + 29779840);   // 3276800
  u16*   Wih     = (u16*)(ws + 33056640);   // 2097152
  u16*   Wfc     = (u16*)(ws + 39348096);   // 30720000
  u16*   Ebf     = (u16*)(ws + 70068096);   // 262144  -> end 70330240

  sort_k<<<1, 256, 0, stream>>>(cap_len, caps, out, sind, dlen, trow, zmap,
                                nact, flags, tilend);
  // combined converts/gathers + Wfc: 4544512 float4-units -> 17752 blocks
  prep_k<<<17752, 256, 0, stream>>>(w_ih, encoder_out, emb, w_fc, caps, sind,
                                    Wih, Ebf, Xb, Wfc);
  // xW = X @ w_ih^T + b_ih + b_hh  (all steps at once)
  gemm_bt<<<dim3(25, 16), 256, 0, stream>>>(Xb, Wih, 3200, 2048, 512,
                                            xW, b_ih, b_hh);
  // fused: in-kernel h0/c0 + 50 LSTM steps (64 blocks) + streaming FC (192)
  lstm_fc<<<256, 256, 0, stream>>>(w_hh, w_init_h, w_init_c, b_init_h, b_init_c,
                                   Ebf, xW, (u32*)hbuf, (u32*)Hs, flags,
                                   Wfc, b_fc, trow, zmap, nact, tilend, out);
}